// Round 12
// baseline (71509.180 us; speedup 1.0000x reference)
//
#include <hip/hip_runtime.h>
#include <hip/hip_fp16.h>

typedef _Float16 f16;
typedef _Float16 f16x2 __attribute__((ext_vector_type(2)));
typedef _Float16 f16x8 __attribute__((ext_vector_type(8)));
typedef float f32x4 __attribute__((ext_vector_type(4)));
typedef unsigned int u32;

#define BATCH 32
#define SEQT  2048
#define DIN   256
#define HU    256
#define G4    1024          // 4*H
#define MROWS (BATCH*SEQT)  // 65536

// ---- workspace layout (bytes) ----
// xw   f16 [65536][1024] @ 0            134217728
// xh   f16 [65536][256]  @ 134217728     33554432
// wt   f16 [1024][256]   @ 167772160       524288
// upk4 u32 [32][1024][4] @ 168296448       524288   (chunk-major U)
#define WS_XW 0
#define WS_XH 134217728UL
#define WS_WT 167772160UL
#define WS_UP 168296448UL
#define WS_NEED 168820736UL

// ---------------- prep kernels ----------------
// upk4 chunk-major: chunk c (= h-pairs 4c..4c+3 = k 8c..8c+7), col j:
// dword (c*1024 + j)*4 + (p&3). One uint4 = one chunk of one column;
// lane t reads upk4[c*1024+t] -> consecutive lanes, consecutive 16 B.
__global__ void pack_u(const float* __restrict__ U, u32* __restrict__ upk4) {
    int idx = blockIdx.x * 256 + threadIdx.x;      // 128*1024
    int p = idx >> 10, j = idx & 1023;
    f16x2 h;
    h.x = (f16)U[(2 * p) * G4 + j];
    h.y = (f16)U[(2 * p + 1) * G4 + j];
    upk4[(((p >> 2) * 1024 + j) << 2) + (p & 3)] = __builtin_bit_cast(u32, h);
}

__global__ void conv_x(const float* __restrict__ x, f16* __restrict__ xh) {
    int idx = blockIdx.x * 256 + threadIdx.x;      // 65536*32
    int row = idx >> 5, c = idx & 31;
    const float4* src = (const float4*)(x + row * 256 + c * 8);
    float4 v0 = src[0], v1 = src[1];
    f16x8 o;
    o[0] = (f16)v0.x; o[1] = (f16)v0.y; o[2] = (f16)v0.z; o[3] = (f16)v0.w;
    o[4] = (f16)v1.x; o[5] = (f16)v1.y; o[6] = (f16)v1.z; o[7] = (f16)v1.w;
    *(f16x8*)(xh + row * 256 + c * 8) = o;
}

__global__ void conv_w(const float* __restrict__ W, f16* __restrict__ wt) {
    int idx = blockIdx.x * 256 + threadIdx.x;      // 1024*32
    int j = idx >> 5, c = idx & 31;
    f16x8 o;
#pragma unroll
    for (int i = 0; i < 8; ++i) o[i] = (f16)W[(c * 8 + i) * G4 + j];
    *(f16x8*)(wt + j * 256 + c * 8) = o;
}

// ---------------- xW GEMM: [65536,256]x[256,1024] fp16 MFMA ----------------
__launch_bounds__(256)
__global__ void gemm_xw(const f16* __restrict__ xh, const f16* __restrict__ wt,
                        const float* __restrict__ bias, f16* __restrict__ xw) {
    __shared__ __align__(16) f16 As[128 * 256];   // 64 KB, swizzled chunks
    __shared__ __align__(16) f16 Bs[128 * 256];   // 64 KB
    int mt = blockIdx.x, nt = blockIdx.y;
    int t = threadIdx.x, lane = t & 63, w = t >> 6;

    const uint4* Ag = (const uint4*)(xh + (size_t)mt * 128 * 256);
    const uint4* Bg = (const uint4*)(wt + (size_t)nt * 128 * 256);
#pragma unroll
    for (int i = 0; i < 16; ++i) {
        int o16 = t + i * 256;            // 16B chunk id 0..4095
        int row = o16 >> 5, c = o16 & 31;
        uint4 va = Ag[o16];
        uint4 vb = Bg[o16];
        int sw = c ^ (row & 7);
        *(uint4*)((char*)As + row * 512 + sw * 16) = va;
        *(uint4*)((char*)Bs + row * 512 + sw * 16) = vb;
    }
    __syncthreads();

    int wr = w >> 1, wc = w & 1;
    f32x4 acc[4][4];
#pragma unroll
    for (int mi = 0; mi < 4; ++mi)
#pragma unroll
        for (int ni = 0; ni < 4; ++ni) acc[mi][ni] = (f32x4){0.f, 0.f, 0.f, 0.f};

    int rA = lane & 15;
    int kg = lane >> 4;    // 0..3 -> k-offset group of 8
#pragma unroll
    for (int ks = 0; ks < 8; ++ks) {
        f16x8 af[4], bf[4];
#pragma unroll
        for (int mi = 0; mi < 4; ++mi) {
            int row = wr * 64 + mi * 16 + rA;
            int c = ks * 4 + kg;
            af[mi] = *(const f16x8*)((const char*)As + row * 512 + ((c ^ (row & 7)) * 16));
        }
#pragma unroll
        for (int ni = 0; ni < 4; ++ni) {
            int row = wc * 64 + ni * 16 + rA;
            int c = ks * 4 + kg;
            bf[ni] = *(const f16x8*)((const char*)Bs + row * 512 + ((c ^ (row & 7)) * 16));
        }
#pragma unroll
        for (int mi = 0; mi < 4; ++mi)
#pragma unroll
            for (int ni = 0; ni < 4; ++ni)
                acc[mi][ni] = __builtin_amdgcn_mfma_f32_16x16x32_f16(af[mi], bf[ni], acc[mi][ni], 0, 0, 0);
    }

    // epilogue: C/D layout col=lane&15, row=(lane>>4)*4+q
    int r4 = (lane >> 4) * 4, cc = lane & 15;
    float bv[4];
#pragma unroll
    for (int ni = 0; ni < 4; ++ni) bv[ni] = bias[nt * 128 + wc * 64 + ni * 16 + cc];
#pragma unroll
    for (int mi = 0; mi < 4; ++mi)
#pragma unroll
        for (int ni = 0; ni < 4; ++ni)
#pragma unroll
            for (int q = 0; q < 4; ++q) {
                int grow = mt * 128 + wr * 64 + mi * 16 + r4 + q;
                int gcol = nt * 128 + wc * 64 + ni * 16 + cc;
                xw[(size_t)grow * 1024 + gcol] = (f16)(acc[mi][ni][q] + bv[ni]);
            }
}

// ---------------- recurrence ----------------
__device__ __forceinline__ float fdot2u(u32 u, u32 h, float acc) {
    return __builtin_amdgcn_fdot2(__builtin_bit_cast(f16x2, u),
                                  __builtin_bit_cast(f16x2, h), acc, false);
}
__device__ __forceinline__ float sigm(float x) {
    return 1.0f / (1.0f + __expf(-x));
}
__device__ __forceinline__ float tanh_f(float x) {
    x = fminf(fmaxf(x, -15.0f), 15.0f);
    float e = __expf(2.0f * x);
    return (e - 1.0f) / (e + 1.0f);
}

// ---- R12 = R6 topology + explicit 6-deep streamed-chunk pipeline ----
// R6 (4.04ms, best): single WG/batch, no sync; per-step cost = ~360KB U
// re-stream from L1/L2 with latency-serialized issue (VGPR grant 64 ->
// ~8 loads in flight). R10/R11 proved cross-WG per-step sync costs
// ~1.5us -> multi-WG designs lose. Here the re-stream is explicit and
// software-pipelined: 6 named uint4 slots (24 VGPR in flight, rule-#20
// safe: all compile-time indices); after consuming slot c%6, issue the
// load for chunk c+6 into it. Distance 6 x (~50 cyc/SIMD per chunk at 4
// waves) ~ L2 latency -> loads land just in time. Chunks 23..31 stay in
// LDS (stride-36, measured 0 conflicts). 1024 thr; gate=t>>8 uniform.

#define MACP(c, slot, nc) do {                        \
    uint4 hv = *(const uint4*)&hpair[4*(c)];          \
    a0 = fdot2u(slot.x, hv.x, a0);                    \
    a1 = fdot2u(slot.y, hv.y, a1);                    \
    a2 = fdot2u(slot.z, hv.z, a2);                    \
    a3 = fdot2u(slot.w, hv.w, a3);                    \
    slot = upk4[(nc) * 1024 + t];                     \
} while (0)
#define MACF(c, slot) do {                            \
    uint4 hv = *(const uint4*)&hpair[4*(c)];          \
    a0 = fdot2u(slot.x, hv.x, a0);                    \
    a1 = fdot2u(slot.y, hv.y, a1);                    \
    a2 = fdot2u(slot.z, hv.z, a2);                    \
    a3 = fdot2u(slot.w, hv.w, a3);                    \
} while (0)

__launch_bounds__(1024)
__global__ void lstm_rec(const uint4* __restrict__ upk4, const f16* __restrict__ xw,
                         float* __restrict__ out) {
    __shared__ __align__(16) u32 ulds[1024 * 36];  // 144 KB: chunks 23..31, stride 36
    __shared__ __align__(16) u32 hpair[128];       // 256 h as f16 pairs
    __shared__ __align__(16) float gbuf[1024];     // activated gates

    int b = blockIdx.x, t = threadIdx.x;

#pragma unroll
    for (int ch = 0; ch < 9; ++ch) {
        uint4 v = upk4[(23 + ch) * 1024 + t];
        *(uint4*)&ulds[t * 36 + ch * 4] = v;
    }
    if (t < 128) hpair[t] = 0u;

    float c_state = 0.0f;
    const f16* xp = xw + (size_t)b * SEQT * G4;
    float* op = out + (size_t)b * SEQT * HU;
    f16 xa = xp[t];

    // pipeline prologue: slots hold chunks 0..5
    uint4 p0 = upk4[0 * 1024 + t], p1 = upk4[1 * 1024 + t],
          p2 = upk4[2 * 1024 + t], p3 = upk4[3 * 1024 + t],
          p4 = upk4[4 * 1024 + t], p5 = upk4[5 * 1024 + t];
    __syncthreads();

    for (int st = 0; st < SEQT; ++st) {
        float a0 = (float)xa, a1 = 0.f, a2 = 0.f, a3 = 0.f;
        if (st < SEQT - 1) xa = xp[G4 + t];   // prefetch next step's xw
        xp += G4;

        // streamed chunks 0..22, 6-deep rotating pipeline
        MACP(0, p0, 6);   MACP(1, p1, 7);   MACP(2, p2, 8);
        MACP(3, p3, 9);   MACP(4, p4, 10);  MACP(5, p5, 11);
        MACP(6, p0, 12);  MACP(7, p1, 13);  MACP(8, p2, 14);
        MACP(9, p3, 15);  MACP(10, p4, 16); MACP(11, p5, 17);
        MACP(12, p0, 18); MACP(13, p1, 19); MACP(14, p2, 20);
        MACP(15, p3, 21); MACP(16, p4, 22);
        MACF(17, p5);
        MACF(18, p0); MACF(19, p1); MACF(20, p2); MACF(21, p3);
        MACF(22, p4);

        // chunks 23..31 from LDS
#pragma unroll
        for (int ch = 0; ch < 9; ++ch) {
            uint4 hv = *(const uint4*)&hpair[92 + ch * 4];
            uint4 u4 = *(const uint4*)&ulds[t * 36 + ch * 4];
            a0 = fdot2u(u4.x, hv.x, a0);
            a1 = fdot2u(u4.y, hv.y, a1);
            a2 = fdot2u(u4.z, hv.z, a2);
            a3 = fdot2u(u4.w, hv.w, a3);
        }
        float a = (a0 + a1) + (a2 + a3);

        // refill pipeline for next step (hidden under activation/barriers)
        if (st < SEQT - 1) {
            p0 = upk4[0 * 1024 + t]; p1 = upk4[1 * 1024 + t];
            p2 = upk4[2 * 1024 + t]; p3 = upk4[3 * 1024 + t];
            p4 = upk4[4 * 1024 + t]; p5 = upk4[5 * 1024 + t];
        }

        // activation: gate = t>>8 (wave-uniform). g-gate (2) is tanh.
        float act = ((t >> 8) == 2) ? tanh_f(a) : sigm(a);
        gbuf[t] = act;
        __syncthreads();

        if (t < 256) {
            float gi = gbuf[t];
            float gf = gbuf[256 + t];
            float gg = gbuf[512 + t];
            float go = gbuf[768 + t];
            c_state = gf * c_state + gi * gg;
            float h = go * tanh_f(c_state);
            op[t] = h;
            ((f16*)hpair)[t] = (f16)h;
        }
        op += HU;
        __syncthreads();
    }
}

extern "C" void kernel_launch(void* const* d_in, const int* in_sizes, int n_in,
                              void* d_out, int out_size, void* d_ws, size_t ws_size,
                              hipStream_t stream) {
    const float* x    = (const float*)d_in[0];
    const float* W    = (const float*)d_in[1];
    const float* U    = (const float*)d_in[2];
    const float* bias = (const float*)d_in[3];
    float* out = (float*)d_out;

    if (ws_size < WS_NEED) return;  // fail loudly rather than corrupt
    char* ws = (char*)d_ws;
    f16* xw    = (f16*)(ws + WS_XW);
    f16* xh    = (f16*)(ws + WS_XH);
    f16* wt    = (f16*)(ws + WS_WT);
    u32* upk4  = (u32*)(ws + WS_UP);

    pack_u<<<512, 256, 0, stream>>>(U, upk4);
    conv_x<<<8192, 256, 0, stream>>>(x, xh);
    conv_w<<<128, 256, 0, stream>>>(W, wt);
    gemm_xw<<<dim3(512, 8), 256, 0, stream>>>(xh, wt, bias, xw);
    lstm_rec<<<32, 1024, 0, stream>>>((const uint4*)upk4, xw, out);
}

// Round 13
// 7891.499 us; speedup vs baseline: 9.0615x; 9.0615x over previous
//
#include <hip/hip_runtime.h>
#include <hip/hip_fp16.h>

typedef _Float16 f16;
typedef _Float16 f16x2 __attribute__((ext_vector_type(2)));
typedef _Float16 f16x8 __attribute__((ext_vector_type(8)));
typedef float f32x4 __attribute__((ext_vector_type(4)));
typedef unsigned int u32;

#define BATCH 32
#define SEQT  2048
#define DIN   256
#define HU    256
#define G4    1024          // 4*H
#define MROWS (BATCH*SEQT)  // 65536

// ---- workspace layout (bytes) ----
// xw   f16 [65536][1024] @ 0            134217728
// xh   f16 [65536][256]  @ 134217728     33554432
// wt   f16 [1024][256]   @ 167772160       524288
// upk4 u32 [32][1024][4] @ 168296448       524288   (chunk-major U)
#define WS_XW 0
#define WS_XH 134217728UL
#define WS_WT 167772160UL
#define WS_UP 168296448UL
#define WS_NEED 168820736UL

// ---------------- prep kernels ----------------
// upk4 chunk-major: chunk c (= h-pairs 4c..4c+3 = k 8c..8c+7), col j:
// dword (c*1024 + j)*4 + (p&3). One uint4 = one chunk of one column;
// lane t reads upk4[c*1024+t] -> consecutive lanes, consecutive 16 B.
__global__ void pack_u(const float* __restrict__ U, u32* __restrict__ upk4) {
    int idx = blockIdx.x * 256 + threadIdx.x;      // 128*1024
    int p = idx >> 10, j = idx & 1023;
    f16x2 h;
    h.x = (f16)U[(2 * p) * G4 + j];
    h.y = (f16)U[(2 * p + 1) * G4 + j];
    upk4[(((p >> 2) * 1024 + j) << 2) + (p & 3)] = __builtin_bit_cast(u32, h);
}

__global__ void conv_x(const float* __restrict__ x, f16* __restrict__ xh) {
    int idx = blockIdx.x * 256 + threadIdx.x;      // 65536*32
    int row = idx >> 5, c = idx & 31;
    const float4* src = (const float4*)(x + row * 256 + c * 8);
    float4 v0 = src[0], v1 = src[1];
    f16x8 o;
    o[0] = (f16)v0.x; o[1] = (f16)v0.y; o[2] = (f16)v0.z; o[3] = (f16)v0.w;
    o[4] = (f16)v1.x; o[5] = (f16)v1.y; o[6] = (f16)v1.z; o[7] = (f16)v1.w;
    *(f16x8*)(xh + row * 256 + c * 8) = o;
}

__global__ void conv_w(const float* __restrict__ W, f16* __restrict__ wt) {
    int idx = blockIdx.x * 256 + threadIdx.x;      // 1024*32
    int j = idx >> 5, c = idx & 31;
    f16x8 o;
#pragma unroll
    for (int i = 0; i < 8; ++i) o[i] = (f16)W[(c * 8 + i) * G4 + j];
    *(f16x8*)(wt + j * 256 + c * 8) = o;
}

// ---------------- xW GEMM: [65536,256]x[256,1024] fp16 MFMA ----------------
__launch_bounds__(256)
__global__ void gemm_xw(const f16* __restrict__ xh, const f16* __restrict__ wt,
                        const float* __restrict__ bias, f16* __restrict__ xw) {
    __shared__ __align__(16) f16 As[128 * 256];   // 64 KB, swizzled chunks
    __shared__ __align__(16) f16 Bs[128 * 256];   // 64 KB
    int mt = blockIdx.x, nt = blockIdx.y;
    int t = threadIdx.x, lane = t & 63, w = t >> 6;

    const uint4* Ag = (const uint4*)(xh + (size_t)mt * 128 * 256);
    const uint4* Bg = (const uint4*)(wt + (size_t)nt * 128 * 256);
#pragma unroll
    for (int i = 0; i < 16; ++i) {
        int o16 = t + i * 256;            // 16B chunk id 0..4095
        int row = o16 >> 5, c = o16 & 31;
        uint4 va = Ag[o16];
        uint4 vb = Bg[o16];
        int sw = c ^ (row & 7);
        *(uint4*)((char*)As + row * 512 + sw * 16) = va;
        *(uint4*)((char*)Bs + row * 512 + sw * 16) = vb;
    }
    __syncthreads();

    int wr = w >> 1, wc = w & 1;
    f32x4 acc[4][4];
#pragma unroll
    for (int mi = 0; mi < 4; ++mi)
#pragma unroll
        for (int ni = 0; ni < 4; ++ni) acc[mi][ni] = (f32x4){0.f, 0.f, 0.f, 0.f};

    int rA = lane & 15;
    int kg = lane >> 4;    // 0..3 -> k-offset group of 8
#pragma unroll
    for (int ks = 0; ks < 8; ++ks) {
        f16x8 af[4], bf[4];
#pragma unroll
        for (int mi = 0; mi < 4; ++mi) {
            int row = wr * 64 + mi * 16 + rA;
            int c = ks * 4 + kg;
            af[mi] = *(const f16x8*)((const char*)As + row * 512 + ((c ^ (row & 7)) * 16));
        }
#pragma unroll
        for (int ni = 0; ni < 4; ++ni) {
            int row = wc * 64 + ni * 16 + rA;
            int c = ks * 4 + kg;
            bf[ni] = *(const f16x8*)((const char*)Bs + row * 512 + ((c ^ (row & 7)) * 16));
        }
#pragma unroll
        for (int mi = 0; mi < 4; ++mi)
#pragma unroll
            for (int ni = 0; ni < 4; ++ni)
                acc[mi][ni] = __builtin_amdgcn_mfma_f32_16x16x32_f16(af[mi], bf[ni], acc[mi][ni], 0, 0, 0);
    }

    // epilogue: C/D layout col=lane&15, row=(lane>>4)*4+q
    int r4 = (lane >> 4) * 4, cc = lane & 15;
    float bv[4];
#pragma unroll
    for (int ni = 0; ni < 4; ++ni) bv[ni] = bias[nt * 128 + wc * 64 + ni * 16 + cc];
#pragma unroll
    for (int mi = 0; mi < 4; ++mi)
#pragma unroll
        for (int ni = 0; ni < 4; ++ni)
#pragma unroll
            for (int q = 0; q < 4; ++q) {
                int grow = mt * 128 + wr * 64 + mi * 16 + r4 + q;
                int gcol = nt * 128 + wc * 64 + ni * 16 + cc;
                xw[(size_t)grow * 1024 + gcol] = (f16)(acc[mi][ni][q] + bv[ni]);
            }
}

// ---------------- recurrence ----------------
__device__ __forceinline__ float fdot2u(u32 u, u32 h, float acc) {
    return __builtin_amdgcn_fdot2(__builtin_bit_cast(f16x2, u),
                                  __builtin_bit_cast(f16x2, h), acc, false);
}
__device__ __forceinline__ float sigm(float x) {
    return 1.0f / (1.0f + __expf(-x));
}
__device__ __forceinline__ float tanh_f(float x) {
    x = fminf(fmaxf(x, -15.0f), 15.0f);
    float e = __expf(2.0f * x);
    return (e - 1.0f) / (e + 1.0f);
}

// ---- R13 = R6 topology, ALL 32 U chunks streamed, LDS = h only ----
// Cost model from R6-R12 counters: step(4730cyc) = LDS-pipe-bound:
// 16 waves x (32 hv-broadcasts ~5cyc + 9 LDS col-chunk b128 @12cyc).
// The 9 LDS-resident U chunks cost ~1728 cyc/step of the saturated DS
// pipe while the L2 stream (R8: not binding; 4x fewer instrs = null)
// has slack. So: stream ALL 32 chunks (512 KB/step/CU from L2, ~35%
// of per-XCD L2 BW at 4 CUs/XCD), keep in LDS only hpair (h broadcast,
// 512 B) + gbuf (gate exchange, 4 KB). Predicted LDS/step ~2600 cyc,
// VALU ~2850 -> step ~3000-3400. No register residency is attempted
// anywhere (R5/R12 proved that spills); the compiler's natural
// load->MAC remat schedule (R6-proven) is relied on as-is.

__launch_bounds__(1024)
__global__ void lstm_rec(const uint4* __restrict__ upk4, const f16* __restrict__ xw,
                         float* __restrict__ out) {
    __shared__ __align__(16) u32 hpair[128];       // 256 h as f16 pairs
    __shared__ __align__(16) float gbuf[1024];     // activated gates

    int b = blockIdx.x, t = threadIdx.x;
    if (t < 128) hpair[t] = 0u;

    float c_state = 0.0f;
    const f16* xp = xw + (size_t)b * SEQT * G4;
    float* op = out + (size_t)b * SEQT * HU;
    f16 xa = xp[t];
    __syncthreads();

    for (int st = 0; st < SEQT; ++st) {
        float a0 = (float)xa, a1 = 0.f, a2 = 0.f, a3 = 0.f;
        if (st < SEQT - 1) xa = xp[G4 + t];   // prefetch next step's xw
        xp += G4;

        // all 32 chunks streamed from L2; hv broadcast from LDS
#pragma unroll
        for (int c = 0; c < 32; ++c) {
            uint4 u4 = upk4[c * 1024 + t];
            uint4 hv = *(const uint4*)&hpair[c << 2];
            a0 = fdot2u(u4.x, hv.x, a0);
            a1 = fdot2u(u4.y, hv.y, a1);
            a2 = fdot2u(u4.z, hv.z, a2);
            a3 = fdot2u(u4.w, hv.w, a3);
        }
        float a = (a0 + a1) + (a2 + a3);

        // activation: gate = t>>8 (wave-uniform). g-gate (2) is tanh.
        float act = ((t >> 8) == 2) ? tanh_f(a) : sigm(a);
        gbuf[t] = act;
        __syncthreads();

        if (t < 256) {
            float gi = gbuf[t];
            float gf = gbuf[256 + t];
            float gg = gbuf[512 + t];
            float go = gbuf[768 + t];
            c_state = gf * c_state + gi * gg;
            float h = go * tanh_f(c_state);
            op[t] = h;
            ((f16*)hpair)[t] = (f16)h;
        }
        op += HU;
        __syncthreads();
    }
}

extern "C" void kernel_launch(void* const* d_in, const int* in_sizes, int n_in,
                              void* d_out, int out_size, void* d_ws, size_t ws_size,
                              hipStream_t stream) {
    const float* x    = (const float*)d_in[0];
    const float* W    = (const float*)d_in[1];
    const float* U    = (const float*)d_in[2];
    const float* bias = (const float*)d_in[3];
    float* out = (float*)d_out;

    if (ws_size < WS_NEED) return;  // fail loudly rather than corrupt
    char* ws = (char*)d_ws;
    f16* xw    = (f16*)(ws + WS_XW);
    f16* xh    = (f16*)(ws + WS_XH);
    f16* wt    = (f16*)(ws + WS_WT);
    u32* upk4  = (u32*)(ws + WS_UP);

    pack_u<<<512, 256, 0, stream>>>(U, upk4);
    conv_x<<<8192, 256, 0, stream>>>(x, xh);
    conv_w<<<128, 256, 0, stream>>>(W, wt);
    gemm_xw<<<dim3(512, 8), 256, 0, stream>>>(xh, wt, bias, xw);
    lstm_rec<<<32, 1024, 0, stream>>>((const uint4*)upk4, xw, out);
}